// Round 9
// baseline (364.919 us; speedup 1.0000x reference)
//
#include <hip/hip_runtime.h>
#include <cstdint>

#define NLAYER 3
#define DMODEL 256
#define NHEAD 8
#define HEADD 32
#define FFDIM 1024
#define BATCH 32
#define SEQ 512
#define MTOK (BATCH*SEQ)   // 16384

typedef __attribute__((ext_vector_type(8))) __bf16 bf16x8;
typedef __attribute__((ext_vector_type(4))) __bf16 bf16x4;
typedef __attribute__((ext_vector_type(4))) float f32x4;
typedef __attribute__((ext_vector_type(16))) float f32x16;

typedef __attribute__((address_space(1))) const uint8_t ga_t;
typedef __attribute__((address_space(3))) uint8_t la_t;
__device__ __forceinline__ void gll16(const void* g, void* l) {
    __builtin_amdgcn_global_load_lds((ga_t*)g, (la_t*)l, 16, 0, 0);
}

// ---------------------------------------------------------------------------
// Prep:
//  - Wq/Wk/Wv -> wqf: MFMA A-fragment packing per (layer, head): layout
//    [l][h][t(3)][ks(16)][512], frag lane cl=out-dim(0..31), kh=lane>>5,
//    elements = W[k=ks*16+kh*8+j][h*32+cl].
//  - Wo -> wot transposed bf16 [N][K] (for gemm_ln).
//  - W1/W2 -> w1f/w2f B-fragment packing (as round 8).
//  - bias concat bqkv, input projection -> hA.
// ---------------------------------------------------------------------------
__global__ __launch_bounds__(256)
void prep_kernel(const float* __restrict__ Wq, const float* __restrict__ Wk,
                 const float* __restrict__ Wv, const float* __restrict__ Wo,
                 const float* __restrict__ W1, const float* __restrict__ W2,
                 const float* __restrict__ bq, const float* __restrict__ bk,
                 const float* __restrict__ bv,
                 __bf16* __restrict__ wqf, __bf16* __restrict__ wot,
                 __bf16* __restrict__ w1f, __bf16* __restrict__ w2f,
                 float* __restrict__ bqkv,
                 const float* __restrict__ x, const float* __restrict__ Win,
                 const float* __restrict__ bin, __bf16* __restrict__ h16)
{
    const int bid = blockIdx.x;
    const int tid = threadIdx.x;
    if (bid >= 2313) {
        const int m0 = (bid - 2313) * 8;
        const float bv_ = bin[tid];
#pragma unroll
        for (int p = 0; p < 8; ++p) {
            const int m = m0 + p;
            const float* xr = x + (size_t)m * 5;
            float acc = bv_;
#pragma unroll
            for (int k = 0; k < 5; ++k) acc += xr[k] * Win[k * DMODEL + tid];
            h16[(size_t)m * DMODEL + tid] = (__bf16)acc;
        }
        return;
    }
    if (bid >= 3 * 768) {
        int idx = (bid - 3 * 768) * 256 + tid;  // 0..2303
        int l = idx / 768, j = idx % 768;
        float v = (j < 256) ? bq[l * 256 + j]
                : (j < 512) ? bk[l * 256 + j - 256]
                            : bv[l * 256 + j - 512];
        bqkv[idx] = v;
        return;
    }
    const int l = bid / 768;
    const int rr = bid % 768;
    __shared__ float tile[32][33];
    const int c = tid & 31, rbase = tid >> 5;

    if (rr < 192) {
        // ---- Wq/Wk/Wv A-fragment packing ----
        const int ty = rr >> 6;                 // 0=q 1=k 2=v
        const int t = rr & 63;                  // tile index, 8x8 tiles
        const float* src = (ty == 0 ? Wq : ty == 1 ? Wk : Wv) + (size_t)l * 65536;
        const int tk = t >> 3, tj = t & 7;      // k-tile, n-tile(=head)
#pragma unroll
        for (int p = 0; p < 4; ++p) {
            int kr = rbase + p * 8;
            tile[kr][c] = src[(size_t)(tk * 32 + kr) * 256 + tj * 32 + c];
        }
        __syncthreads();
        if (tid < 128) {
            const int lane = tid & 63, ksl = tid >> 6;
            const int cl = lane & 31, kh = lane >> 5;
            bf16x8 v;
#pragma unroll
            for (int j = 0; j < 8; ++j) v[j] = (__bf16)tile[ksl * 16 + kh * 8 + j][cl];
            // layout: (((l*8 + h)*3 + ty)*16 + ks)*512 + lane*8
            *(bf16x8*)(wqf + ((size_t)(((l * 8 + tj) * 3 + ty) * 16
                              + tk * 2 + ksl)) * 512 + lane * 8) = v;
        }
        return;
    }
    if (rr < 256) {
        // ---- Wo transposed bf16 [256][256] ----
        const int t = rr - 192;
        const float* src = Wo + (size_t)l * 65536;
        __bf16* dst = wot + (size_t)l * 65536;
        const int tk = t >> 3, tj = t & 7;
#pragma unroll
        for (int p = 0; p < 4; ++p) {
            int kr = rbase + p * 8;
            tile[kr][c] = src[(size_t)(tk * 32 + kr) * 256 + tj * 32 + c];
        }
        __syncthreads();
#pragma unroll
        for (int p = 0; p < 4; ++p) {
            int nr = rbase + p * 8;
            dst[(size_t)(tj * 32 + nr) * 256 + tk * 32 + c] = (__bf16)tile[c][nr];
        }
        return;
    }
    // ---- fragment-packed W1 / W2 (B-operand order, as round 8) ----
    const float* src; __bf16* dst; int N, KT, t;
    if (rr < 512) { t = rr - 256; src = W1 + (size_t)l * 262144;
                    dst = w1f + (size_t)l * 262144; N = 1024; KT = 8; }
    else          { t = rr - 512; src = W2 + (size_t)l * 262144;
                    dst = w2f + (size_t)l * 262144; N = 256;  KT = 32; }
    const int tn = N >> 5;
    const int tk = t / tn, tj = t % tn;
#pragma unroll
    for (int p = 0; p < 4; ++p) {
        int kr = rbase + p * 8;
        tile[kr][c] = src[(size_t)(tk * 32 + kr) * N + tj * 32 + c];
    }
    __syncthreads();
    if (tid < 128) {
        const int l_n = tid >> 2, k8 = tid & 3;
        const int n = tj * 32 + l_n;
        bf16x8 v;
#pragma unroll
        for (int j = 0; j < 8; ++j) v[j] = (__bf16)tile[k8 * 8 + j][l_n];
        *(bf16x8*)(dst + ((size_t)((n >> 4) * KT + tk) * 64 + k8 * 16 + (n & 15)) * 8) = v;
    }
}

// ---------------------------------------------------------------------------
// Fused QKV projection + flash attention. One block per (b,h), 1024 thr =
// 16 waves, each wave owns 32 tokens (as queries) and computes that chunk's
// Q/K/V in phase 1.
// Phase 1: Ws = 48 KB W-fragment panel (LDS, staged once). Per wave, 16
//   k-steps: token B-frag from global (hA rows), 3 A-frags from Ws, 3x
//   mfma_32x32x16 -> D[dim][token] (col=token). K -> Ks[key][dim],
//   V -> Vt[dim][key] (scalar scatter), Q round-trips per-wave LDS -> B-frag
//   registers. Union buffer: Ws (phase 1) then per-wave Q/P scratch.
// Phase 2: unchanged flash loop (S^T = Ks x Q, no online max, O^T = Vt x P).
// LDS: Ks 40960 + Vt 33280 + Un 49152 + mask 2048 = 122.5 KB, 1 block/CU.
// ---------------------------------------------------------------------------
__global__ __launch_bounds__(1024)
void attn_kernel(const __bf16* __restrict__ hA, const __bf16* __restrict__ wqf,
                 const float* __restrict__ bqkv, const int* __restrict__ mask,
                 __bf16* __restrict__ ao)
{
    __shared__ __bf16 Ks[512 * 40];                              // 40960 B
    __shared__ __bf16 Vt[32 * 520];                              // 33280 B
    __shared__ __attribute__((aligned(16))) __bf16 Un[3*16*512]; // 49152 B
    __shared__ float maskadd[512];                               //  2048 B

    const int b = blockIdx.x >> 3;
    const int h = blockIdx.x & 7;
    const int t = threadIdx.x;
    const int lane = t & 63;
    const int wave = t >> 6;             // 0..15
    const int cl = lane & 31;
    const int kh = lane >> 5;
    const float scale = 0.17677669529663687f;  // 1/sqrt(32)

    // ---- stage W fragment panel (48 KB) ----
    {
        const __bf16* wsrc = wqf + (size_t)h * 24576;   // (h*3)*16*512
#pragma unroll
        for (int p = 0; p < 3; ++p) {
            const int chunk = p * 1024 + t;
            gll16(wsrc + (size_t)chunk * 8, Un + (p * 1024 + wave * 64) * 8);
        }
    }
    if (t < 512) maskadd[t] = mask[b * SEQ + t] ? -1e30f : 0.f;
    __syncthreads();

    // ---- phase 1: compute Q/K/V for this wave's 32 tokens ----
    const int tok0 = wave * 32;
    const size_t arow = ((size_t)(b * SEQ + tok0 + cl)) * 256;
    f32x16 aQ, aK, aV;
#pragma unroll
    for (int i = 0; i < 16; ++i) { aQ[i] = 0.f; aK[i] = 0.f; aV[i] = 0.f; }
#pragma unroll
    for (int ks = 0; ks < 16; ++ks) {
        bf16x8 tf = *(const bf16x8*)(hA + arow + ks * 16 + kh * 8);
        bf16x8 wq = *(const bf16x8*)(Un + (0 * 16 + ks) * 512 + lane * 8);
        bf16x8 wk = *(const bf16x8*)(Un + (1 * 16 + ks) * 512 + lane * 8);
        bf16x8 wv = *(const bf16x8*)(Un + (2 * 16 + ks) * 512 + lane * 8);
        aQ = __builtin_amdgcn_mfma_f32_32x32x16_bf16(wq, tf, aQ, 0, 0, 0);
        aK = __builtin_amdgcn_mfma_f32_32x32x16_bf16(wk, tf, aK, 0, 0, 0);
        aV = __builtin_amdgcn_mfma_f32_32x32x16_bf16(wv, tf, aV, 0, 0, 0);
    }
    // biases + write K (Ks[key][dim]) and V (Vt[dim][key])
#pragma unroll
    for (int r = 0; r < 16; ++r) {
        const int rdim = (r & 3) + 8 * (r >> 2) + 4 * kh;
        Ks[(tok0 + cl) * 40 + rdim] = (__bf16)(aK[r] + bqkv[256 + h * 32 + rdim]);
        Vt[rdim * 520 + tok0 + cl]  = (__bf16)(aV[r] + bqkv[512 + h * 32 + rdim]);
    }
    __syncthreads();   // all Ws reads done -> Un reusable as per-wave scratch

    // ---- Q -> per-wave LDS (stride 32) -> B-frag registers ----
    __bf16* Pw = Un + wave * 1024;      // 2 KB per wave
#pragma unroll
    for (int r = 0; r < 16; ++r) {
        const int rdim = (r & 3) + 8 * (r >> 2) + 4 * kh;
        Pw[cl * 32 + rdim] = (__bf16)(aQ[r] + bqkv[h * 32 + rdim]);
    }
    bf16x8 qf0 = *(const bf16x8*)(Pw + cl * 32 + kh * 8);
    bf16x8 qf1 = *(const bf16x8*)(Pw + cl * 32 + 16 + kh * 8);
    __syncthreads();   // Ks/Vt visible to all waves

    // ---- phase 2: flash loop ----
    f32x16 oacc;
#pragma unroll
    for (int i = 0; i < 16; ++i) oacc[i] = 0.f;
    float lsum = 0.f;

    for (int kt = 0; kt < SEQ; kt += 32) {
        bf16x8 kf0 = *(const bf16x8*)(Ks + (kt + cl) * 40 + kh * 8);
        bf16x8 kf1 = *(const bf16x8*)(Ks + (kt + cl) * 40 + 16 + kh * 8);
        f32x16 s;
#pragma unroll
        for (int i = 0; i < 16; ++i) s[i] = 0.f;
        s = __builtin_amdgcn_mfma_f32_32x32x16_bf16(kf0, qf0, s, 0, 0, 0);
        s = __builtin_amdgcn_mfma_f32_32x32x16_bf16(kf1, qf1, s, 0, 0, 0);
        float pv[16];
#pragma unroll
        for (int g = 0; g < 4; ++g) {
            f32x4 mv = *(const f32x4*)(maskadd + kt + 8 * g + 4 * kh);
#pragma unroll
            for (int r = 0; r < 4; ++r) {
                float e = __expf(s[g * 4 + r] * scale + mv[r]);
                pv[g * 4 + r] = e;
                lsum += e;
            }
        }
#pragma unroll
        for (int g = 0; g < 4; ++g) {
            bf16x4 pb;
#pragma unroll
            for (int r = 0; r < 4; ++r) pb[r] = (__bf16)pv[g * 4 + r];
            *(bf16x4*)(Pw + cl * 32 + 8 * g + 4 * kh) = pb;
        }
        bf16x8 pf0 = *(const bf16x8*)(Pw + cl * 32 + kh * 8);
        bf16x8 pf1 = *(const bf16x8*)(Pw + cl * 32 + 16 + kh * 8);
        bf16x8 vf0 = *(const bf16x8*)(Vt + cl * 520 + kt + kh * 8);
        bf16x8 vf1 = *(const bf16x8*)(Vt + cl * 520 + kt + 16 + kh * 8);
        oacc = __builtin_amdgcn_mfma_f32_32x32x16_bf16(vf0, pf0, oacc, 0, 0, 0);
        oacc = __builtin_amdgcn_mfma_f32_32x32x16_bf16(vf1, pf1, oacc, 0, 0, 0);
    }

    lsum += __shfl_xor(lsum, 32);
    const float inv = (lsum > 0.f) ? 1.f / lsum : 0.f;
    __bf16* orow = ao + (size_t)(b * SEQ + tok0 + cl) * DMODEL + h * 32;
#pragma unroll
    for (int g = 0; g < 4; ++g) {
        bf16x4 w;
#pragma unroll
        for (int r = 0; r < 4; ++r) w[r] = (__bf16)(oacc[g * 4 + r] * inv);
        *(bf16x4*)(orow + 8 * g + 4 * kh) = w;
    }
}

// ---------------------------------------------------------------------------
// Fused GEMM + residual + LayerNorm, N=256 (Wo path). Unchanged.
// ---------------------------------------------------------------------------
template<int LAST>
__global__ __launch_bounds__(256, 4)
void gemm_ln_kernel(const __bf16* __restrict__ A, const __bf16* __restrict__ Bt,
                    const float* __restrict__ bias, const __bf16* __restrict__ res,
                    const float* __restrict__ g, const float* __restrict__ be,
                    __bf16* __restrict__ out16, float* __restrict__ out32, int K)
{
    __shared__ __bf16 As[32 * 64];
    __shared__ __bf16 Bs[256 * 64];
    __shared__ float red[32 * 8];
    const int tid = threadIdx.x;
    const int m0 = blockIdx.x * 32;
    const int lane = tid & 63;
    const int wave = tid >> 6;
    const int wn = wave * 64;
    const int fr = lane & 15;
    const int quad = lane >> 4;
    const int lr = lane >> 3;
    const int qg = (lane & 7) ^ lr;
    const int frs = fr & 7;

    const __bf16* Ab = A  + (size_t)(m0 + wave * 8 + lr) * K + qg * 8;
    const __bf16* Bb = Bt + (size_t)(wave * 64 + lr) * K + qg * 8;

    f32x4 acc[2][4];
#pragma unroll
    for (int i = 0; i < 2; ++i)
#pragma unroll
        for (int j = 0; j < 4; ++j)
#pragma unroll
            for (int r = 0; r < 4; ++r) acc[i][j][r] = 0.f;

    for (int k0 = 0; k0 < K; k0 += 64) {
        gll16(Ab + k0, As + wave * 512);
#pragma unroll
        for (int p = 0; p < 8; ++p)
            gll16(Bb + (size_t)p * 8 * K + k0, Bs + (wave * 8 + p) * 512);
        __syncthreads();
#pragma unroll
        for (int kk = 0; kk < 2; ++kk) {
            bf16x8 af[2], bfr[4];
#pragma unroll
            for (int i = 0; i < 2; ++i) {
                int row = i * 16 + fr;
                af[i] = *(const bf16x8*)(As + row * 64 + (((kk * 4 + quad) ^ frs) * 8));
            }
#pragma unroll
            for (int j = 0; j < 4; ++j) {
                int row = wn + j * 16 + fr;
                bfr[j] = *(const bf16x8*)(Bs + row * 64 + (((kk * 4 + quad) ^ frs) * 8));
            }
#pragma unroll
            for (int i = 0; i < 2; ++i)
#pragma unroll
                for (int j = 0; j < 4; ++j)
                    acc[i][j] = __builtin_amdgcn_mfma_f32_16x16x32_bf16(
                        af[i], bfr[j], acc[i][j], 0, 0, 0);
        }
        __syncthreads();
    }

    float bv[4];
#pragma unroll
    for (int j = 0; j < 4; ++j) bv[j] = bias[wn + j * 16 + fr];

#pragma unroll
    for (int i = 0; i < 2; ++i) {
#pragma unroll
        for (int r = 0; r < 4; ++r) {
            const int row = i * 16 + quad * 4 + r;
            float ps = 0.f, pq = 0.f;
#pragma unroll
            for (int j = 0; j < 4; ++j) {
                const int gc = wn + j * 16 + fr;
                float v = acc[i][j][r] + bv[j]
                        + (float)res[(size_t)(m0 + row) * DMODEL + gc];
                acc[i][j][r] = v;
                ps += v;
                pq += v * v;
            }
#pragma unroll
            for (int off = 1; off < 16; off <<= 1) {
                ps += __shfl_xor(ps, off, 64);
                pq += __shfl_xor(pq, off, 64);
            }
            if (fr == 0) {
                red[row * 8 + wave * 2]     = ps;
                red[row * 8 + wave * 2 + 1] = pq;
            }
        }
    }
    __syncthreads();

#pragma unroll
    for (int i = 0; i < 2; ++i) {
#pragma unroll
        for (int r = 0; r < 4; ++r) {
            const int row = i * 16 + quad * 4 + r;
            f32x4 a = *(const f32x4*)(red + row * 8);
            f32x4 b2 = *(const f32x4*)(red + row * 8 + 4);
            const float s  = a[0] + a[2] + b2[0] + b2[2];
            const float sq = a[1] + a[3] + b2[1] + b2[3];
            const float mu = s * (1.f / DMODEL);
            const float var = sq * (1.f / DMODEL) - mu * mu;
            const float rs = rsqrtf(var + 1e-5f);
#pragma unroll
            for (int j = 0; j < 4; ++j) {
                const int gc = wn + j * 16 + fr;
                float y = (acc[i][j][r] - mu) * rs * g[gc] + be[gc];
                if (LAST) out32[(size_t)(m0 + row) * DMODEL + gc] = y;
                else      out16[(size_t)(m0 + row) * DMODEL + gc] = (__bf16)y;
            }
        }
    }
}

// ---------------------------------------------------------------------------
// Fully fused FF block (round 8, unchanged): out = LN(res + relu(A@W1+c1)@W2 + c2)
// ---------------------------------------------------------------------------
template<int LAST>
__global__ __launch_bounds__(256, 3)
void ff_kernel(const __bf16* __restrict__ A, const __bf16* __restrict__ w1f,
               const float* __restrict__ c1, const __bf16* __restrict__ w2f,
               const float* __restrict__ c2, const __bf16* __restrict__ res,
               const float* __restrict__ g, const float* __restrict__ be,
               __bf16* __restrict__ out16, float* __restrict__ out32)
{
    __shared__ __attribute__((aligned(16))) __bf16 As[4][32 * 64];  // 16 KB
    __shared__ __attribute__((aligned(16))) __bf16 P[32 * 136];     // 8.5 KB
    __shared__ float c1s[1024];                                      // 4 KB
    __shared__ float red[32 * 8];                                    // 1 KB
    const int tid = threadIdx.x;
    const int lane = tid & 63;
    const int wave = tid >> 6;
    const int fr = lane & 15;
    const int quad = lane >> 4;
    const int m0 = blockIdx.x * 32;
    const int frs = fr & 7;

    {
        const int lr = lane >> 3, pos = lane & 7;
#pragma unroll
        for (int c4 = 0; c4 < 4; ++c4) {
            const int row = c4 * 8 + lr;
            const int gsw = pos ^ (row & 7);
            gll16(A + (size_t)(m0 + row) * 256 + wave * 64 + gsw * 8,
                  &As[wave][c4 * 8 * 64]);
        }
    }
    *(f32x4*)(c1s + tid * 4) = *(const f32x4*)(c1 + tid * 4);

    f32x4 acc2[2][4];
#pragma unroll
    for (int i = 0; i < 2; ++i)
#pragma unroll
        for (int j = 0; j < 4; ++j)
#pragma unroll
            for (int r = 0; r < 4; ++r) acc2[i][j][r] = 0.f;
    __syncthreads();

    for (int ch = 0; ch < 8; ++ch) {
        f32x4 acc1[2][2];
#pragma unroll
        for (int i = 0; i < 2; ++i)
#pragma unroll
            for (int j = 0; j < 2; ++j)
#pragma unroll
                for (int r = 0; r < 4; ++r) acc1[i][j][r] = 0.f;
#pragma unroll
        for (int ks = 0; ks < 8; ++ks) {
            bf16x8 af[2], bfr[2];
#pragma unroll
            for (int i = 0; i < 2; ++i)
                af[i] = *(const bf16x8*)(&As[ks >> 1][(i * 16 + fr) * 64
                         + ((((ks & 1) * 4 + quad) ^ frs) * 8)]);
#pragma unroll
            for (int j = 0; j < 2; ++j) {
                const int ntf = ch * 8 + wave * 2 + j;
                bfr[j] = *(const bf16x8*)(w1f + ((size_t)(ntf * 8 + ks) * 64 + lane) * 8);
            }
#pragma unroll
            for (int i = 0; i < 2; ++i)
#pragma unroll
                for (int j = 0; j < 2; ++j)
                    acc1[i][j] = __builtin_amdgcn_mfma_f32_16x16x32_bf16(
                        af[i], bfr[j], acc1[i][j], 0, 0, 0);
        }
#pragma unroll
        for (int j = 0; j < 2; ++j) {
            const float cb = c1s[ch * 128 + wave * 32 + j * 16 + fr];
#pragma unroll
            for (int i = 0; i < 2; ++i)
#pragma unroll
                for (int r = 0; r < 4; ++r) {
                    const int rowm = i * 16 + quad * 4 + r;
                    float v = fmaxf(acc1[i][j][r] + cb, 0.f);
                    P[rowm * 136 + wave * 32 + j * 16 + fr] = (__bf16)v;
                }
        }
        __syncthreads();
#pragma unroll
        for (int ks = 0; ks < 4; ++ks) {
            bf16x8 pf[2], wf[4];
#pragma unroll
            for (int i = 0; i < 2; ++i)
                pf[i] = *(const bf16x8*)(P + (i * 16 + fr) * 136 + ks * 32 + quad * 8);
#pragma unroll
            for (int j = 0; j < 4; ++j) {
                const int ntg = wave * 4 + j;
                const int kt = ch * 4 + ks;
                wf[j] = *(const bf16x8*)(w2f + ((size_t)(ntg * 32 + kt) * 64 + lane) * 8);
            }
#pragma unroll
            for (int i = 0; i < 2; ++i)
#pragma unroll
                for (int j = 0; j < 4; ++j)
                    acc2[i][j] = __builtin_amdgcn_mfma_f32_16x16x32_bf16(
                        pf[i], wf[j], acc2[i][j], 0, 0, 0);
        }
        __syncthreads();
    }

    const int wn = wave * 64;
    float bv[4];
#pragma unroll
    for (int j = 0; j < 4; ++j) bv[j] = c2[wn + j * 16 + fr];

#pragma unroll
    for (int i = 0; i < 2; ++i) {
#pragma unroll
        for (int r = 0; r < 4; ++r) {
            const int row = i * 16 + quad * 4 + r;
            float ps = 0.f, pq = 0.f;
#pragma unroll
            for (int j = 0; j < 4; ++j) {
                const int gc = wn + j * 16 + fr;
                float v = acc2[i][j][r] + bv[j]
                        + (float)res[(size_t)(m0 + row) * DMODEL + gc];
                acc2[i][j][r] = v;
                ps += v;
                pq += v * v;
            }
#pragma unroll
            for (int off = 1; off < 16; off <<= 1) {
                ps += __shfl_xor(ps, off, 64);
                pq += __shfl_xor(pq, off, 64);
            }
            if (fr == 0) {
                red[row * 8 + wave * 2]     = ps;
                red[row * 8 + wave * 2 + 1] = pq;
            }
        }
    }
    __syncthreads();

#pragma unroll
    for (int i = 0; i < 2; ++i) {
#pragma unroll
        for (int r = 0; r < 4; ++r) {
            const int row = i * 16 + quad * 4 + r;
            f32x4 a = *(const f32x4*)(red + row * 8);
            f32x4 b2 = *(const f32x4*)(red + row * 8 + 4);
            const float s  = a[0] + a[2] + b2[0] + b2[2];
            const float sq = a[1] + a[3] + b2[1] + b2[3];
            const float mu = s * (1.f / DMODEL);
            const float var = sq * (1.f / DMODEL) - mu * mu;
            const float rs = rsqrtf(var + 1e-5f);
#pragma unroll
            for (int j = 0; j < 4; ++j) {
                const int gc = wn + j * 16 + fr;
                float y = (acc2[i][j][r] - mu) * rs * g[gc] + be[gc];
                if (LAST) out32[(size_t)(m0 + row) * DMODEL + gc] = y;
                else      out16[(size_t)(m0 + row) * DMODEL + gc] = (__bf16)y;
            }
        }
    }
}

// ---------------------------------------------------------------------------
extern "C" void kernel_launch(void* const* d_in, const int* in_sizes, int n_in,
                              void* d_out, int out_size, void* d_ws, size_t ws_size,
                              hipStream_t stream)
{
    const float* x   = (const float*)d_in[0];
    const int*   mask= (const int*)d_in[1];
    const float* Win = (const float*)d_in[2];
    const float* bin = (const float*)d_in[3];
    const float* Wq  = (const float*)d_in[4];
    const float* bq  = (const float*)d_in[5];
    const float* Wk  = (const float*)d_in[6];
    const float* bk  = (const float*)d_in[7];
    const float* Wv  = (const float*)d_in[8];
    const float* bv  = (const float*)d_in[9];
    const float* Wo  = (const float*)d_in[10];
    const float* bo  = (const float*)d_in[11];
    const float* g1  = (const float*)d_in[12];
    const float* b1  = (const float*)d_in[13];
    const float* W1  = (const float*)d_in[14];
    const float* c1  = (const float*)d_in[15];
    const float* W2  = (const float*)d_in[16];
    const float* c2  = (const float*)d_in[17];
    const float* g2  = (const float*)d_in[18];
    const float* b2  = (const float*)d_in[19];

    char* ws = (char*)d_ws;
    size_t off = 0;
    auto alloc = [&](size_t bytes) -> void* {
        void* p = ws + off;
        off += (bytes + 255) & ~(size_t)255;
        return p;
    };
    __bf16* hA   = (__bf16*)alloc((size_t)MTOK * 256 * 2);  // residual stream
    __bf16* hB   = (__bf16*)alloc((size_t)MTOK * 256 * 2);  // LN1 output
    __bf16* ao   = (__bf16*)alloc((size_t)MTOK * 256 * 2);
    __bf16* wqf  = (__bf16*)alloc((size_t)3 * 8 * 3 * 16 * 512 * 2);  // 1.2 MB
    __bf16* wot  = (__bf16*)alloc((size_t)3 * 256 * 256 * 2);
    __bf16* w1f  = (__bf16*)alloc((size_t)3 * 1024 * 256 * 2);
    __bf16* w2f  = (__bf16*)alloc((size_t)3 * 256 * 1024 * 2);
    float*  bqkv = (float*)alloc((size_t)3 * 768 * 4);

    prep_kernel<<<dim3(2313 + MTOK / 8), dim3(256), 0, stream>>>(
        Wq, Wk, Wv, Wo, W1, W2, bq, bk, bv, wqf, wot, w1f, w2f, bqkv,
        x, Win, bin, hA);

    for (int l = 0; l < NLAYER; ++l) {
        // fused QKV + attention (one block per (b,h))
        attn_kernel<<<dim3(256), dim3(1024), 0, stream>>>(
            hA, wqf + (size_t)l * 8 * 3 * 16 * 512, bqkv + l * 768, mask, ao);
        // Wo + residual + LN1 fused: hB = LN(hA + ao@Wo + bo)
        gemm_ln_kernel<0><<<dim3(MTOK / 32), dim3(256), 0, stream>>>(
            ao, wot + (size_t)l * 65536, bo + l * 256, hA,
            g1 + l * 256, b1 + l * 256, hB, nullptr, 256);
        // Fused FF block: hA = LN(hB + relu(hB@W1+c1)@W2 + c2)  (last -> d_out)
        if (l == 2) {
            ff_kernel<1><<<dim3(MTOK / 32), dim3(256), 0, stream>>>(
                hB, w1f + (size_t)l * 262144, c1 + l * 1024,
                w2f + (size_t)l * 262144, c2 + l * 256, hB,
                g2 + l * 256, b2 + l * 256, nullptr, (float*)d_out);
        } else {
            ff_kernel<0><<<dim3(MTOK / 32), dim3(256), 0, stream>>>(
                hB, w1f + (size_t)l * 262144, c1 + l * 1024,
                w2f + (size_t)l * 262144, c2 + l * 256, hB,
                g2 + l * 256, b2 + l * 256, hA, nullptr);
        }
    }
}

// Round 10
// 345.052 us; speedup vs baseline: 1.0576x; 1.0576x over previous
//
#include <hip/hip_runtime.h>
#include <cstdint>

#define NLAYER 3
#define DMODEL 256
#define NHEAD 8
#define HEADD 32
#define FFDIM 1024
#define BATCH 32
#define SEQ 512
#define MTOK (BATCH*SEQ)   // 16384

typedef __attribute__((ext_vector_type(8))) __bf16 bf16x8;
typedef __attribute__((ext_vector_type(4))) __bf16 bf16x4;
typedef __attribute__((ext_vector_type(4))) float f32x4;
typedef __attribute__((ext_vector_type(16))) float f32x16;

typedef __attribute__((address_space(1))) const uint8_t ga_t;
typedef __attribute__((address_space(3))) uint8_t la_t;
__device__ __forceinline__ void gll16(const void* g, void* l) {
    __builtin_amdgcn_global_load_lds((ga_t*)g, (la_t*)l, 16, 0, 0);
}

// ---------------------------------------------------------------------------
// Prep:
//  - Wq/Wk/Wv -> wqf: A-fragment packing per (layer, head) [32x32x16 shape].
//  - Wo -> wot transposed bf16 [N][K] (for gemm_ln).
//  - W1 -> w1f: A-operand frags (m=ff):  frag(ft,ks): lane elem j =
//      W1[k=ks*32+quad*8+j][ff=ft*16+fr],  offset ((l*64+ft)*8+ks)*512+lane*8.
//  - W2 -> w2f: A-operand frags (m=dm):  frag(dt,kt): lane elem j =
//      W2[ff=kt*32+quad*8+j][dm=dt*16+fr], offset ((l*16+dt)*32+kt)*512+lane*8.
//  - bias concat bqkv, input projection -> hA.
// ---------------------------------------------------------------------------
__global__ __launch_bounds__(256)
void prep_kernel(const float* __restrict__ Wq, const float* __restrict__ Wk,
                 const float* __restrict__ Wv, const float* __restrict__ Wo,
                 const float* __restrict__ W1, const float* __restrict__ W2,
                 const float* __restrict__ bq, const float* __restrict__ bk,
                 const float* __restrict__ bv,
                 __bf16* __restrict__ wqf, __bf16* __restrict__ wot,
                 __bf16* __restrict__ w1f, __bf16* __restrict__ w2f,
                 float* __restrict__ bqkv,
                 const float* __restrict__ x, const float* __restrict__ Win,
                 const float* __restrict__ bin, __bf16* __restrict__ h16)
{
    const int bid = blockIdx.x;
    const int tid = threadIdx.x;
    if (bid >= 2313) {
        const int m0 = (bid - 2313) * 8;
        const float bv_ = bin[tid];
#pragma unroll
        for (int p = 0; p < 8; ++p) {
            const int m = m0 + p;
            const float* xr = x + (size_t)m * 5;
            float acc = bv_;
#pragma unroll
            for (int k = 0; k < 5; ++k) acc += xr[k] * Win[k * DMODEL + tid];
            h16[(size_t)m * DMODEL + tid] = (__bf16)acc;
        }
        return;
    }
    if (bid >= 3 * 768) {
        int idx = (bid - 3 * 768) * 256 + tid;  // 0..2303
        int l = idx / 768, j = idx % 768;
        float v = (j < 256) ? bq[l * 256 + j]
                : (j < 512) ? bk[l * 256 + j - 256]
                            : bv[l * 256 + j - 512];
        bqkv[idx] = v;
        return;
    }
    const int l = bid / 768;
    const int rr = bid % 768;
    __shared__ float tile[32][33];
    const int c = tid & 31, rbase = tid >> 5;

    if (rr < 192) {
        // ---- Wq/Wk/Wv A-fragment packing (32x32x16 shape) ----
        const int ty = rr >> 6;
        const int t = rr & 63;
        const float* src = (ty == 0 ? Wq : ty == 1 ? Wk : Wv) + (size_t)l * 65536;
        const int tk = t >> 3, tj = t & 7;
#pragma unroll
        for (int p = 0; p < 4; ++p) {
            int kr = rbase + p * 8;
            tile[kr][c] = src[(size_t)(tk * 32 + kr) * 256 + tj * 32 + c];
        }
        __syncthreads();
        if (tid < 128) {
            const int lane = tid & 63, ksl = tid >> 6;
            const int cl = lane & 31, kh = lane >> 5;
            bf16x8 v;
#pragma unroll
            for (int j = 0; j < 8; ++j) v[j] = (__bf16)tile[ksl * 16 + kh * 8 + j][cl];
            *(bf16x8*)(wqf + ((size_t)(((l * 8 + tj) * 3 + ty) * 16
                              + tk * 2 + ksl)) * 512 + lane * 8) = v;
        }
        return;
    }
    if (rr < 256) {
        // ---- Wo transposed bf16 [256][256] ----
        const int t = rr - 192;
        const float* src = Wo + (size_t)l * 65536;
        __bf16* dst = wot + (size_t)l * 65536;
        const int tk = t >> 3, tj = t & 7;
#pragma unroll
        for (int p = 0; p < 4; ++p) {
            int kr = rbase + p * 8;
            tile[kr][c] = src[(size_t)(tk * 32 + kr) * 256 + tj * 32 + c];
        }
        __syncthreads();
#pragma unroll
        for (int p = 0; p < 4; ++p) {
            int nr = rbase + p * 8;
            dst[(size_t)(tj * 32 + nr) * 256 + tk * 32 + c] = (__bf16)tile[c][nr];
        }
        return;
    }
    // ---- A-operand fragment packing for W1 / W2 ----
    const float* src; int NN, tk, tj, t;
    if (rr < 512) { t = rr - 256; src = W1 + (size_t)l * 262144;
                    NN = 1024; tk = t >> 5; tj = t & 31; }
    else          { t = rr - 512; src = W2 + (size_t)l * 262144;
                    NN = 256;  tk = t >> 3; tj = t & 7; }
#pragma unroll
    for (int p = 0; p < 4; ++p) {
        int kr = rbase + p * 8;
        tile[kr][c] = src[(size_t)(tk * 32 + kr) * NN + tj * 32 + c];
    }
    __syncthreads();
    if (tid < 128) {
        const int sub = tid >> 6, lane = tid & 63;
        const int fq = lane >> 4, ff = lane & 15;
        bf16x8 v;
#pragma unroll
        for (int j = 0; j < 8; ++j) v[j] = (__bf16)tile[fq * 8 + j][sub * 16 + ff];
        if (rr < 512)
            *(bf16x8*)(w1f + ((size_t)(l * 64 + tj * 2 + sub) * 8 + tk) * 512 + lane * 8) = v;
        else
            *(bf16x8*)(w2f + ((size_t)(l * 16 + tj * 2 + sub) * 32 + tk) * 512 + lane * 8) = v;
    }
}

// ---------------------------------------------------------------------------
// Fused QKV projection + flash attention (round 9, unchanged).
// ---------------------------------------------------------------------------
__global__ __launch_bounds__(1024)
void attn_kernel(const __bf16* __restrict__ hA, const __bf16* __restrict__ wqf,
                 const float* __restrict__ bqkv, const int* __restrict__ mask,
                 __bf16* __restrict__ ao)
{
    __shared__ __bf16 Ks[512 * 40];
    __shared__ __bf16 Vt[32 * 520];
    __shared__ __attribute__((aligned(16))) __bf16 Un[3*16*512];
    __shared__ float maskadd[512];

    const int b = blockIdx.x >> 3;
    const int h = blockIdx.x & 7;
    const int t = threadIdx.x;
    const int lane = t & 63;
    const int wave = t >> 6;
    const int cl = lane & 31;
    const int kh = lane >> 5;
    const float scale = 0.17677669529663687f;

    {
        const __bf16* wsrc = wqf + (size_t)h * 24576;
#pragma unroll
        for (int p = 0; p < 3; ++p) {
            const int chunk = p * 1024 + t;
            gll16(wsrc + (size_t)chunk * 8, Un + (p * 1024 + wave * 64) * 8);
        }
    }
    if (t < 512) maskadd[t] = mask[b * SEQ + t] ? -1e30f : 0.f;
    __syncthreads();

    const int tok0 = wave * 32;
    const size_t arow = ((size_t)(b * SEQ + tok0 + cl)) * 256;
    f32x16 aQ, aK, aV;
#pragma unroll
    for (int i = 0; i < 16; ++i) { aQ[i] = 0.f; aK[i] = 0.f; aV[i] = 0.f; }
#pragma unroll
    for (int ks = 0; ks < 16; ++ks) {
        bf16x8 tf = *(const bf16x8*)(hA + arow + ks * 16 + kh * 8);
        bf16x8 wq = *(const bf16x8*)(Un + (0 * 16 + ks) * 512 + lane * 8);
        bf16x8 wk = *(const bf16x8*)(Un + (1 * 16 + ks) * 512 + lane * 8);
        bf16x8 wv = *(const bf16x8*)(Un + (2 * 16 + ks) * 512 + lane * 8);
        aQ = __builtin_amdgcn_mfma_f32_32x32x16_bf16(wq, tf, aQ, 0, 0, 0);
        aK = __builtin_amdgcn_mfma_f32_32x32x16_bf16(wk, tf, aK, 0, 0, 0);
        aV = __builtin_amdgcn_mfma_f32_32x32x16_bf16(wv, tf, aV, 0, 0, 0);
    }
#pragma unroll
    for (int r = 0; r < 16; ++r) {
        const int rdim = (r & 3) + 8 * (r >> 2) + 4 * kh;
        Ks[(tok0 + cl) * 40 + rdim] = (__bf16)(aK[r] + bqkv[256 + h * 32 + rdim]);
        Vt[rdim * 520 + tok0 + cl]  = (__bf16)(aV[r] + bqkv[512 + h * 32 + rdim]);
    }
    __syncthreads();

    __bf16* Pw = Un + wave * 1024;
#pragma unroll
    for (int r = 0; r < 16; ++r) {
        const int rdim = (r & 3) + 8 * (r >> 2) + 4 * kh;
        Pw[cl * 32 + rdim] = (__bf16)(aQ[r] + bqkv[h * 32 + rdim]);
    }
    bf16x8 qf0 = *(const bf16x8*)(Pw + cl * 32 + kh * 8);
    bf16x8 qf1 = *(const bf16x8*)(Pw + cl * 32 + 16 + kh * 8);
    __syncthreads();

    f32x16 oacc;
#pragma unroll
    for (int i = 0; i < 16; ++i) oacc[i] = 0.f;
    float lsum = 0.f;

    for (int kt = 0; kt < SEQ; kt += 32) {
        bf16x8 kf0 = *(const bf16x8*)(Ks + (kt + cl) * 40 + kh * 8);
        bf16x8 kf1 = *(const bf16x8*)(Ks + (kt + cl) * 40 + 16 + kh * 8);
        f32x16 s;
#pragma unroll
        for (int i = 0; i < 16; ++i) s[i] = 0.f;
        s = __builtin_amdgcn_mfma_f32_32x32x16_bf16(kf0, qf0, s, 0, 0, 0);
        s = __builtin_amdgcn_mfma_f32_32x32x16_bf16(kf1, qf1, s, 0, 0, 0);
        float pv[16];
#pragma unroll
        for (int g = 0; g < 4; ++g) {
            f32x4 mv = *(const f32x4*)(maskadd + kt + 8 * g + 4 * kh);
#pragma unroll
            for (int r = 0; r < 4; ++r) {
                float e = __expf(s[g * 4 + r] * scale + mv[r]);
                pv[g * 4 + r] = e;
                lsum += e;
            }
        }
#pragma unroll
        for (int g = 0; g < 4; ++g) {
            bf16x4 pb;
#pragma unroll
            for (int r = 0; r < 4; ++r) pb[r] = (__bf16)pv[g * 4 + r];
            *(bf16x4*)(Pw + cl * 32 + 8 * g + 4 * kh) = pb;
        }
        bf16x8 pf0 = *(const bf16x8*)(Pw + cl * 32 + kh * 8);
        bf16x8 pf1 = *(const bf16x8*)(Pw + cl * 32 + 16 + kh * 8);
        bf16x8 vf0 = *(const bf16x8*)(Vt + cl * 520 + kt + kh * 8);
        bf16x8 vf1 = *(const bf16x8*)(Vt + cl * 520 + kt + 16 + kh * 8);
        oacc = __builtin_amdgcn_mfma_f32_32x32x16_bf16(vf0, pf0, oacc, 0, 0, 0);
        oacc = __builtin_amdgcn_mfma_f32_32x32x16_bf16(vf1, pf1, oacc, 0, 0, 0);
    }

    lsum += __shfl_xor(lsum, 32);
    const float inv = (lsum > 0.f) ? 1.f / lsum : 0.f;
    __bf16* orow = ao + (size_t)(b * SEQ + tok0 + cl) * DMODEL + h * 32;
#pragma unroll
    for (int g = 0; g < 4; ++g) {
        bf16x4 w;
#pragma unroll
        for (int r = 0; r < 4; ++r) w[r] = (__bf16)(oacc[g * 4 + r] * inv);
        *(bf16x4*)(orow + 8 * g + 4 * kh) = w;
    }
}

// ---------------------------------------------------------------------------
// Fused GEMM + residual + LayerNorm, N=256 (Wo path). Unchanged.
// ---------------------------------------------------------------------------
template<int LAST>
__global__ __launch_bounds__(256, 4)
void gemm_ln_kernel(const __bf16* __restrict__ A, const __bf16* __restrict__ Bt,
                    const float* __restrict__ bias, const __bf16* __restrict__ res,
                    const float* __restrict__ g, const float* __restrict__ be,
                    __bf16* __restrict__ out16, float* __restrict__ out32, int K)
{
    __shared__ __bf16 As[32 * 64];
    __shared__ __bf16 Bs[256 * 64];
    __shared__ float red[32 * 8];
    const int tid = threadIdx.x;
    const int m0 = blockIdx.x * 32;
    const int lane = tid & 63;
    const int wave = tid >> 6;
    const int wn = wave * 64;
    const int fr = lane & 15;
    const int quad = lane >> 4;
    const int lr = lane >> 3;
    const int qg = (lane & 7) ^ lr;
    const int frs = fr & 7;

    const __bf16* Ab = A  + (size_t)(m0 + wave * 8 + lr) * K + qg * 8;
    const __bf16* Bb = Bt + (size_t)(wave * 64 + lr) * K + qg * 8;

    f32x4 acc[2][4];
#pragma unroll
    for (int i = 0; i < 2; ++i)
#pragma unroll
        for (int j = 0; j < 4; ++j)
#pragma unroll
            for (int r = 0; r < 4; ++r) acc[i][j][r] = 0.f;

    for (int k0 = 0; k0 < K; k0 += 64) {
        gll16(Ab + k0, As + wave * 512);
#pragma unroll
        for (int p = 0; p < 8; ++p)
            gll16(Bb + (size_t)p * 8 * K + k0, Bs + (wave * 8 + p) * 512);
        __syncthreads();
#pragma unroll
        for (int kk = 0; kk < 2; ++kk) {
            bf16x8 af[2], bfr[4];
#pragma unroll
            for (int i = 0; i < 2; ++i) {
                int row = i * 16 + fr;
                af[i] = *(const bf16x8*)(As + row * 64 + (((kk * 4 + quad) ^ frs) * 8));
            }
#pragma unroll
            for (int j = 0; j < 4; ++j) {
                int row = wn + j * 16 + fr;
                bfr[j] = *(const bf16x8*)(Bs + row * 64 + (((kk * 4 + quad) ^ frs) * 8));
            }
#pragma unroll
            for (int i = 0; i < 2; ++i)
#pragma unroll
                for (int j = 0; j < 4; ++j)
                    acc[i][j] = __builtin_amdgcn_mfma_f32_16x16x32_bf16(
                        af[i], bfr[j], acc[i][j], 0, 0, 0);
        }
        __syncthreads();
    }

    float bv[4];
#pragma unroll
    for (int j = 0; j < 4; ++j) bv[j] = bias[wn + j * 16 + fr];

#pragma unroll
    for (int i = 0; i < 2; ++i) {
#pragma unroll
        for (int r = 0; r < 4; ++r) {
            const int row = i * 16 + quad * 4 + r;
            float ps = 0.f, pq = 0.f;
#pragma unroll
            for (int j = 0; j < 4; ++j) {
                const int gc = wn + j * 16 + fr;
                float v = acc[i][j][r] + bv[j]
                        + (float)res[(size_t)(m0 + row) * DMODEL + gc];
                acc[i][j][r] = v;
                ps += v;
                pq += v * v;
            }
#pragma unroll
            for (int off = 1; off < 16; off <<= 1) {
                ps += __shfl_xor(ps, off, 64);
                pq += __shfl_xor(pq, off, 64);
            }
            if (fr == 0) {
                red[row * 8 + wave * 2]     = ps;
                red[row * 8 + wave * 2 + 1] = pq;
            }
        }
    }
    __syncthreads();

#pragma unroll
    for (int i = 0; i < 2; ++i) {
#pragma unroll
        for (int r = 0; r < 4; ++r) {
            const int row = i * 16 + quad * 4 + r;
            f32x4 a = *(const f32x4*)(red + row * 8);
            f32x4 b2 = *(const f32x4*)(red + row * 8 + 4);
            const float s  = a[0] + a[2] + b2[0] + b2[2];
            const float sq = a[1] + a[3] + b2[1] + b2[3];
            const float mu = s * (1.f / DMODEL);
            const float var = sq * (1.f / DMODEL) - mu * mu;
            const float rs = rsqrtf(var + 1e-5f);
#pragma unroll
            for (int j = 0; j < 4; ++j) {
                const int gc = wn + j * 16 + fr;
                float y = (acc[i][j][r] - mu) * rs * g[gc] + be[gc];
                if (LAST) out32[(size_t)(m0 + row) * DMODEL + gc] = y;
                else      out16[(size_t)(m0 + row) * DMODEL + gc] = (__bf16)y;
            }
        }
    }
}

// ---------------------------------------------------------------------------
// Fused FF block, transposed formulation:
//   out = LN(res + relu(A@W1+c1)@W2 + c2), 32 tokens/block, grid 512.
// W1/W2 are A-operands (pre-packed frags, direct from L2); tokens and the
// relu intermediate P are B-operands -> every LDS access is b64/b128.
// FF1: D[ff][token] (col=token) -> P[token][ff] written b64 (2-way banks).
// FF2: acc2 D[dm][token] (col=token) -> vectorized residual/LN/store.
// W2 frags for chunk ch prefetched into regs before FF1 -> latency hidden.
// P double-buffered -> 1 barrier/chunk.
// ---------------------------------------------------------------------------
template<int LAST>
__global__ __launch_bounds__(256, 2)
void ff_kernel(const __bf16* __restrict__ A, const __bf16* __restrict__ w1A,
               const float* __restrict__ c1, const __bf16* __restrict__ w2A,
               const float* __restrict__ c2, const __bf16* __restrict__ res,
               const float* __restrict__ g, const float* __restrict__ be,
               __bf16* __restrict__ out16, float* __restrict__ out32)
{
    __shared__ __attribute__((aligned(16))) __bf16 As[4][32 * 64];   // 16 KB
    __shared__ __attribute__((aligned(16))) __bf16 P[2][32 * 136];   // 17 KB
    __shared__ float c1s[1024];                                       // 4 KB
    __shared__ float red[32 * 8];                                     // 1 KB
    const int tid = threadIdx.x;
    const int lane = tid & 63;
    const int wave = tid >> 6;
    const int fr = lane & 15;
    const int quad = lane >> 4;
    const int m0 = blockIdx.x * 32;

    // ---- stage A tile (wave w stages k-chunk w), xor swizzle ----
    {
        const int lr = lane >> 3, pos = lane & 7;
#pragma unroll
        for (int c4 = 0; c4 < 4; ++c4) {
            const int row = c4 * 8 + lr;
            const int gsw = pos ^ (row & 7);
            gll16(A + (size_t)(m0 + row) * 256 + wave * 64 + gsw * 8,
                  &As[wave][c4 * 8 * 64]);
        }
    }
    *(f32x4*)(c1s + tid * 4) = *(const f32x4*)(c1 + tid * 4);

    f32x4 acc2[4][2];
#pragma unroll
    for (int jj = 0; jj < 4; ++jj)
#pragma unroll
        for (int tt = 0; tt < 2; ++tt)
#pragma unroll
            for (int r = 0; r < 4; ++r) acc2[jj][tt][r] = 0.f;
    __syncthreads();

#pragma unroll 2
    for (int ch = 0; ch < 8; ++ch) {
        // ---- prefetch W2 A-frags for this chunk (hidden under FF1) ----
        bf16x8 w2r[4][4];
#pragma unroll
        for (int jj = 0; jj < 4; ++jj)
#pragma unroll
            for (int ks = 0; ks < 4; ++ks) {
                const int dt = wave * 4 + jj, kt = ch * 4 + ks;
                w2r[jj][ks] = *(const bf16x8*)(w2A + ((size_t)(dt * 32 + kt) * 64 + lane) * 8);
            }
        // ---- FF1: S^T[ff 32/wave][token 32] ----
        f32x4 acc1[2][2];
#pragma unroll
        for (int i = 0; i < 2; ++i)
#pragma unroll
            for (int j = 0; j < 2; ++j)
#pragma unroll
                for (int r = 0; r < 4; ++r) acc1[i][j][r] = 0.f;
#pragma unroll
        for (int ks = 0; ks < 8; ++ks) {
            bf16x8 w1r[2], tf[2];
#pragma unroll
            for (int i = 0; i < 2; ++i) {
                const int ft = ch * 8 + wave * 2 + i;
                w1r[i] = *(const bf16x8*)(w1A + ((size_t)(ft * 8 + ks) * 64 + lane) * 8);
            }
#pragma unroll
            for (int j = 0; j < 2; ++j)
                tf[j] = *(const bf16x8*)(&As[ks >> 1][(j * 16 + fr) * 64
                          + ((((ks & 1) * 4 + quad) ^ (fr & 7)) * 8)]);
#pragma unroll
            for (int i = 0; i < 2; ++i)
#pragma unroll
                for (int j = 0; j < 2; ++j)
                    acc1[i][j] = __builtin_amdgcn_mfma_f32_16x16x32_bf16(
                        w1r[i], tf[j], acc1[i][j], 0, 0, 0);
        }
        // ---- relu + c1, write P[ch&1][token][ff] as b64 ----
#pragma unroll
        for (int i = 0; i < 2; ++i) {
            f32x4 cb = *(const f32x4*)(c1s + ch * 128 + wave * 32 + i * 16 + quad * 4);
#pragma unroll
            for (int j = 0; j < 2; ++j) {
                bf16x4 pb;
#pragma unroll
                for (int r = 0; r < 4; ++r)
                    pb[r] = (__bf16)fmaxf(acc1[i][j][r] + cb[r], 0.f);
                *(bf16x4*)(&P[ch & 1][(j * 16 + fr) * 136 + wave * 32 + i * 16 + quad * 4]) = pb;
            }
        }
        __syncthreads();
        // ---- FF2 partial: acc2 += W2^T @ P^T (w2 frags already in regs) ----
#pragma unroll
        for (int ks = 0; ks < 4; ++ks) {
            bf16x8 pf[2];
#pragma unroll
            for (int tt = 0; tt < 2; ++tt)
                pf[tt] = *(const bf16x8*)(&P[ch & 1][(tt * 16 + fr) * 136 + ks * 32 + quad * 8]);
#pragma unroll
            for (int jj = 0; jj < 4; ++jj)
#pragma unroll
                for (int tt = 0; tt < 2; ++tt)
                    acc2[jj][tt] = __builtin_amdgcn_mfma_f32_16x16x32_bf16(
                        w2r[jj][ks], pf[tt], acc2[jj][tt], 0, 0, 0);
        }
    }

    // ---- epilogue: + c2 + res (b64), per-token LN, vectorized store ----
    float ps0 = 0.f, pq0 = 0.f, ps1 = 0.f, pq1 = 0.f;
#pragma unroll
    for (int jj = 0; jj < 4; ++jj) {
        f32x4 cb = *(const f32x4*)(c2 + wave * 64 + jj * 16 + quad * 4);
#pragma unroll
        for (int tt = 0; tt < 2; ++tt) {
            bf16x4 rv = *(const bf16x4*)(res + (size_t)(m0 + tt * 16 + fr) * DMODEL
                                         + wave * 64 + jj * 16 + quad * 4);
#pragma unroll
            for (int r = 0; r < 4; ++r) {
                float v = acc2[jj][tt][r] + cb[r] + (float)rv[r];
                acc2[jj][tt][r] = v;
                if (tt == 0) { ps0 += v; pq0 += v * v; }
                else         { ps1 += v; pq1 += v * v; }
            }
        }
    }
    ps0 += __shfl_xor(ps0, 16); ps0 += __shfl_xor(ps0, 32);
    pq0 += __shfl_xor(pq0, 16); pq0 += __shfl_xor(pq0, 32);
    ps1 += __shfl_xor(ps1, 16); ps1 += __shfl_xor(ps1, 32);
    pq1 += __shfl_xor(pq1, 16); pq1 += __shfl_xor(pq1, 32);
    if (quad == 0) {
        red[fr * 8 + wave * 2]            = ps0;
        red[fr * 8 + wave * 2 + 1]        = pq0;
        red[(16 + fr) * 8 + wave * 2]     = ps1;
        red[(16 + fr) * 8 + wave * 2 + 1] = pq1;
    }
    __syncthreads();
    float mu[2], rs_[2];
#pragma unroll
    for (int tt = 0; tt < 2; ++tt) {
        const int tok = tt * 16 + fr;
        f32x4 a = *(const f32x4*)(red + tok * 8);
        f32x4 b2 = *(const f32x4*)(red + tok * 8 + 4);
        const float s  = a[0] + a[2] + b2[0] + b2[2];
        const float sq = a[1] + a[3] + b2[1] + b2[3];
        mu[tt] = s * (1.f / DMODEL);
        const float var = sq * (1.f / DMODEL) - mu[tt] * mu[tt];
        rs_[tt] = rsqrtf(var + 1e-5f);
    }
#pragma unroll
    for (int jj = 0; jj < 4; ++jj) {
        f32x4 gv = *(const f32x4*)(g  + wave * 64 + jj * 16 + quad * 4);
        f32x4 bv = *(const f32x4*)(be + wave * 64 + jj * 16 + quad * 4);
#pragma unroll
        for (int tt = 0; tt < 2; ++tt) {
            const size_t base = (size_t)(m0 + tt * 16 + fr) * DMODEL
                              + wave * 64 + jj * 16 + quad * 4;
            if (LAST) {
                f32x4 y;
#pragma unroll
                for (int r = 0; r < 4; ++r)
                    y[r] = (acc2[jj][tt][r] - mu[tt]) * rs_[tt] * gv[r] + bv[r];
                *(f32x4*)(out32 + base) = y;
            } else {
                bf16x4 y;
#pragma unroll
                for (int r = 0; r < 4; ++r)
                    y[r] = (__bf16)((acc2[jj][tt][r] - mu[tt]) * rs_[tt] * gv[r] + bv[r]);
                *(bf16x4*)(out16 + base) = y;
            }
        }
    }
}

// ---------------------------------------------------------------------------
extern "C" void kernel_launch(void* const* d_in, const int* in_sizes, int n_in,
                              void* d_out, int out_size, void* d_ws, size_t ws_size,
                              hipStream_t stream)
{
    const float* x   = (const float*)d_in[0];
    const int*   mask= (const int*)d_in[1];
    const float* Win = (const float*)d_in[2];
    const float* bin = (const float*)d_in[3];
    const float* Wq  = (const float*)d_in[4];
    const float* bq  = (const float*)d_in[5];
    const float* Wk  = (const float*)d_in[6];
    const float* bk  = (const float*)d_in[7];
    const float* Wv  = (const float*)d_in[8];
    const float* bv  = (const float*)d_in[9];
    const float* Wo  = (const float*)d_in[10];
    const float* bo  = (const float*)d_in[11];
    const float* g1  = (const float*)d_in[12];
    const float* b1  = (const float*)d_in[13];
    const float* W1  = (const float*)d_in[14];
    const float* c1  = (const float*)d_in[15];
    const float* W2  = (const float*)d_in[16];
    const float* c2  = (const float*)d_in[17];
    const float* g2  = (const float*)d_in[18];
    const float* b2  = (const float*)d_in[19];

    char* ws = (char*)d_ws;
    size_t off = 0;
    auto alloc = [&](size_t bytes) -> void* {
        void* p = ws + off;
        off += (bytes + 255) & ~(size_t)255;
        return p;
    };
    __bf16* hA   = (__bf16*)alloc((size_t)MTOK * 256 * 2);
    __bf16* hB   = (__bf16*)alloc((size_t)MTOK * 256 * 2);
    __bf16* ao   = (__bf16*)alloc((size_t)MTOK * 256 * 2);
    __bf16* wqf  = (__bf16*)alloc((size_t)3 * 8 * 3 * 16 * 512 * 2);
    __bf16* wot  = (__bf16*)alloc((size_t)3 * 256 * 256 * 2);
    __bf16* w1f  = (__bf16*)alloc((size_t)3 * 1024 * 256 * 2);
    __bf16* w2f  = (__bf16*)alloc((size_t)3 * 256 * 1024 * 2);
    float*  bqkv = (float*)alloc((size_t)3 * 768 * 4);

    prep_kernel<<<dim3(2313 + MTOK / 8), dim3(256), 0, stream>>>(
        Wq, Wk, Wv, Wo, W1, W2, bq, bk, bv, wqf, wot, w1f, w2f, bqkv,
        x, Win, bin, hA);

    for (int l = 0; l < NLAYER; ++l) {
        // fused QKV + attention (one block per (b,h))
        attn_kernel<<<dim3(256), dim3(1024), 0, stream>>>(
            hA, wqf + (size_t)l * 8 * 3 * 16 * 512, bqkv + l * 768, mask, ao);
        // Wo + residual + LN1 fused: hB = LN(hA + ao@Wo + bo)
        gemm_ln_kernel<0><<<dim3(MTOK / 32), dim3(256), 0, stream>>>(
            ao, wot + (size_t)l * 65536, bo + l * 256, hA,
            g1 + l * 256, b1 + l * 256, hB, nullptr, 256);
        // Fused FF block: hA = LN(hB + relu(hB@W1+c1)@W2 + c2)  (last -> d_out)
        if (l == 2) {
            ff_kernel<1><<<dim3(MTOK / 32), dim3(256), 0, stream>>>(
                hB, w1f + (size_t)l * 262144, c1 + l * 1024,
                w2f + (size_t)l * 262144, c2 + l * 256, hB,
                g2 + l * 256, b2 + l * 256, nullptr, (float*)d_out);
        } else {
            ff_kernel<0><<<dim3(MTOK / 32), dim3(256), 0, stream>>>(
                hB, w1f + (size_t)l * 262144, c1 + l * 1024,
                w2f + (size_t)l * 262144, c2 + l * 256, hB,
                g2 + l * 256, b2 + l * 256, hA, nullptr);
        }
    }
}

// Round 11
// 321.801 us; speedup vs baseline: 1.1340x; 1.0723x over previous
//
#include <hip/hip_runtime.h>
#include <cstdint>

#define NLAYER 3
#define DMODEL 256
#define NHEAD 8
#define HEADD 32
#define FFDIM 1024
#define BATCH 32
#define SEQ 512
#define MTOK (BATCH*SEQ)   // 16384

typedef __attribute__((ext_vector_type(8))) __bf16 bf16x8;
typedef __attribute__((ext_vector_type(4))) __bf16 bf16x4;
typedef __attribute__((ext_vector_type(4))) float f32x4;
typedef __attribute__((ext_vector_type(16))) float f32x16;

typedef __attribute__((address_space(1))) const uint8_t ga_t;
typedef __attribute__((address_space(3))) uint8_t la_t;
__device__ __forceinline__ void gll16(const void* g, void* l) {
    __builtin_amdgcn_global_load_lds((ga_t*)g, (la_t*)l, 16, 0, 0);
}

// ---------------------------------------------------------------------------
// Prep (round 10) + per-batch mask compaction scan:
//  pos[b][t] = compacted slot of key t (or -1 if masked), nb[b] = #unmasked.
// ---------------------------------------------------------------------------
__global__ __launch_bounds__(256)
void prep_kernel(const float* __restrict__ Wq, const float* __restrict__ Wk,
                 const float* __restrict__ Wv, const float* __restrict__ Wo,
                 const float* __restrict__ W1, const float* __restrict__ W2,
                 const float* __restrict__ bq, const float* __restrict__ bk,
                 const float* __restrict__ bv,
                 __bf16* __restrict__ wqf, __bf16* __restrict__ wot,
                 __bf16* __restrict__ w1f, __bf16* __restrict__ w2f,
                 float* __restrict__ bqkv,
                 const float* __restrict__ x, const float* __restrict__ Win,
                 const float* __restrict__ bin, __bf16* __restrict__ h16,
                 const int* __restrict__ mask, int* __restrict__ pos,
                 int* __restrict__ nbp)
{
    const int bid = blockIdx.x;
    const int tid = threadIdx.x;
    if (bid >= 4361) {
        // ---- mask compaction scan, one wave per batch ----
        const int b = bid - 4361;
        if (tid < 64) {
            int base = 0;
#pragma unroll
            for (int c = 0; c < 8; ++c) {
                const int j = c * 64 + tid;
                const bool un = (mask[b * SEQ + j] == 0);
                const unsigned long long bal = __ballot(un);
                const int p = __popcll(bal & ((1ull << tid) - 1ull));
                pos[b * SEQ + j] = un ? (base + p) : -1;
                base += __popcll(bal);
            }
            if (tid == 0) nbp[b] = base;
        }
        return;
    }
    if (bid >= 2313) {
        const int m0 = (bid - 2313) * 8;
        const float bv_ = bin[tid];
#pragma unroll
        for (int p = 0; p < 8; ++p) {
            const int m = m0 + p;
            const float* xr = x + (size_t)m * 5;
            float acc = bv_;
#pragma unroll
            for (int k = 0; k < 5; ++k) acc += xr[k] * Win[k * DMODEL + tid];
            h16[(size_t)m * DMODEL + tid] = (__bf16)acc;
        }
        return;
    }
    if (bid >= 3 * 768) {
        int idx = (bid - 3 * 768) * 256 + tid;  // 0..2303
        int l = idx / 768, j = idx % 768;
        float v = (j < 256) ? bq[l * 256 + j]
                : (j < 512) ? bk[l * 256 + j - 256]
                            : bv[l * 256 + j - 512];
        bqkv[idx] = v;
        return;
    }
    const int l = bid / 768;
    const int rr = bid % 768;
    __shared__ float tile[32][33];
    const int c = tid & 31, rbase = tid >> 5;

    if (rr < 192) {
        const int ty = rr >> 6;
        const int t = rr & 63;
        const float* src = (ty == 0 ? Wq : ty == 1 ? Wk : Wv) + (size_t)l * 65536;
        const int tk = t >> 3, tj = t & 7;
#pragma unroll
        for (int p = 0; p < 4; ++p) {
            int kr = rbase + p * 8;
            tile[kr][c] = src[(size_t)(tk * 32 + kr) * 256 + tj * 32 + c];
        }
        __syncthreads();
        if (tid < 128) {
            const int lane = tid & 63, ksl = tid >> 6;
            const int cl = lane & 31, kh = lane >> 5;
            bf16x8 v;
#pragma unroll
            for (int j = 0; j < 8; ++j) v[j] = (__bf16)tile[ksl * 16 + kh * 8 + j][cl];
            *(bf16x8*)(wqf + ((size_t)(((l * 8 + tj) * 3 + ty) * 16
                              + tk * 2 + ksl)) * 512 + lane * 8) = v;
        }
        return;
    }
    if (rr < 256) {
        const int t = rr - 192;
        const float* src = Wo + (size_t)l * 65536;
        __bf16* dst = wot + (size_t)l * 65536;
        const int tk = t >> 3, tj = t & 7;
#pragma unroll
        for (int p = 0; p < 4; ++p) {
            int kr = rbase + p * 8;
            tile[kr][c] = src[(size_t)(tk * 32 + kr) * 256 + tj * 32 + c];
        }
        __syncthreads();
#pragma unroll
        for (int p = 0; p < 4; ++p) {
            int nr = rbase + p * 8;
            dst[(size_t)(tj * 32 + nr) * 256 + tk * 32 + c] = (__bf16)tile[c][nr];
        }
        return;
    }
    const float* src; int NN, tk, tj, t;
    if (rr < 512) { t = rr - 256; src = W1 + (size_t)l * 262144;
                    NN = 1024; tk = t >> 5; tj = t & 31; }
    else          { t = rr - 512; src = W2 + (size_t)l * 262144;
                    NN = 256;  tk = t >> 3; tj = t & 7; }
#pragma unroll
    for (int p = 0; p < 4; ++p) {
        int kr = rbase + p * 8;
        tile[kr][c] = src[(size_t)(tk * 32 + kr) * NN + tj * 32 + c];
    }
    __syncthreads();
    if (tid < 128) {
        const int sub = tid >> 6, lane = tid & 63;
        const int fq = lane >> 4, ff = lane & 15;
        bf16x8 v;
#pragma unroll
        for (int j = 0; j < 8; ++j) v[j] = (__bf16)tile[fq * 8 + j][sub * 16 + ff];
        if (rr < 512)
            *(bf16x8*)(w1f + ((size_t)(l * 64 + tj * 2 + sub) * 8 + tk) * 512 + lane * 8) = v;
        else
            *(bf16x8*)(w2f + ((size_t)(l * 16 + tj * 2 + sub) * 32 + tk) * 512 + lane * 8) = v;
    }
}

// ---------------------------------------------------------------------------
// Fused QKV + flash attention with mask-compacted KV.
// K/V written to compacted slots (pos[b][t]); phase-2 loops only over
// nkt = ceil(nb/32)*32 slots (~50% fewer iters at p=0.5 masking).
// Scale folded into Q at write. Tail slots zeroed; tailadd guards softmax.
// ---------------------------------------------------------------------------
__global__ __launch_bounds__(1024)
void attn_kernel(const __bf16* __restrict__ hA, const __bf16* __restrict__ wqf,
                 const float* __restrict__ bqkv, const int* __restrict__ pos,
                 const int* __restrict__ nbp, __bf16* __restrict__ ao)
{
    __shared__ __bf16 Ks[512 * 40];
    __shared__ __bf16 Vt[32 * 520];
    __shared__ __attribute__((aligned(16))) __bf16 Un[3*16*512];
    __shared__ float tailadd[512];

    const int b = blockIdx.x >> 3;
    const int h = blockIdx.x & 7;
    const int t = threadIdx.x;
    const int lane = t & 63;
    const int wave = t >> 6;
    const int cl = lane & 31;
    const int kh = lane >> 5;
    const float scale = 0.17677669529663687f;  // 1/sqrt(32)

    const int nb = nbp[b];
    const int nkt = (nb + 31) & ~31;
    const int tailN = nkt - nb;                // 0..31

    {
        const __bf16* wsrc = wqf + (size_t)h * 24576;
#pragma unroll
        for (int p = 0; p < 3; ++p) {
            const int chunk = p * 1024 + t;
            gll16(wsrc + (size_t)chunk * 8, Un + (p * 1024 + wave * 64) * 8);
        }
    }
    if (t < 512) tailadd[t] = (t < nb) ? 0.f : -1e30f;
    // zero tail slots of Ks / Vt (guard against poison in MFMA)
    {
        if (t < tailN * 64) {
            const int row = nb + (t >> 6), d = t & 63;
            if (d < 40) Ks[row * 40 + d] = (__bf16)0.f;
        }
        if (t < tailN * 32) {
            const int col = nb + (t >> 5), d = t & 31;
            Vt[d * 520 + col] = (__bf16)0.f;
        }
    }
    __syncthreads();

    // ---- phase 1: Q/K/V for this wave's 32 tokens ----
    const int tok0 = wave * 32;
    const size_t arow = ((size_t)(b * SEQ + tok0 + cl)) * 256;
    f32x16 aQ, aK, aV;
#pragma unroll
    for (int i = 0; i < 16; ++i) { aQ[i] = 0.f; aK[i] = 0.f; aV[i] = 0.f; }
#pragma unroll
    for (int ks = 0; ks < 16; ++ks) {
        bf16x8 tf = *(const bf16x8*)(hA + arow + ks * 16 + kh * 8);
        bf16x8 wq = *(const bf16x8*)(Un + (0 * 16 + ks) * 512 + lane * 8);
        bf16x8 wk = *(const bf16x8*)(Un + (1 * 16 + ks) * 512 + lane * 8);
        bf16x8 wv = *(const bf16x8*)(Un + (2 * 16 + ks) * 512 + lane * 8);
        aQ = __builtin_amdgcn_mfma_f32_32x32x16_bf16(wq, tf, aQ, 0, 0, 0);
        aK = __builtin_amdgcn_mfma_f32_32x32x16_bf16(wk, tf, aK, 0, 0, 0);
        aV = __builtin_amdgcn_mfma_f32_32x32x16_bf16(wv, tf, aV, 0, 0, 0);
    }
    // K/V -> compacted slots (predicated scatter)
    const int slot = pos[b * SEQ + tok0 + cl];
    if (slot >= 0) {
#pragma unroll
        for (int r = 0; r < 16; ++r) {
            const int rdim = (r & 3) + 8 * (r >> 2) + 4 * kh;
            Ks[slot * 40 + rdim] = (__bf16)(aK[r] + bqkv[256 + h * 32 + rdim]);
            Vt[rdim * 520 + slot] = (__bf16)(aV[r] + bqkv[512 + h * 32 + rdim]);
        }
    }
    __syncthreads();   // Ws reads done -> Un reusable

    // ---- Q (scale folded) -> per-wave LDS -> B-frags ----
    __bf16* Pw = Un + wave * 1024;
#pragma unroll
    for (int r = 0; r < 16; ++r) {
        const int rdim = (r & 3) + 8 * (r >> 2) + 4 * kh;
        Pw[cl * 32 + rdim] = (__bf16)((aQ[r] + bqkv[h * 32 + rdim]) * scale);
    }
    bf16x8 qf0 = *(const bf16x8*)(Pw + cl * 32 + kh * 8);
    bf16x8 qf1 = *(const bf16x8*)(Pw + cl * 32 + 16 + kh * 8);
    __syncthreads();   // Ks/Vt visible

    // ---- phase 2: flash loop over compacted keys ----
    f32x16 oacc;
#pragma unroll
    for (int i = 0; i < 16; ++i) oacc[i] = 0.f;
    float lsum = 0.f;

    for (int kt = 0; kt < nkt; kt += 32) {
        bf16x8 kf0 = *(const bf16x8*)(Ks + (kt + cl) * 40 + kh * 8);
        bf16x8 kf1 = *(const bf16x8*)(Ks + (kt + cl) * 40 + 16 + kh * 8);
        f32x16 s;
#pragma unroll
        for (int i = 0; i < 16; ++i) s[i] = 0.f;
        s = __builtin_amdgcn_mfma_f32_32x32x16_bf16(kf0, qf0, s, 0, 0, 0);
        s = __builtin_amdgcn_mfma_f32_32x32x16_bf16(kf1, qf1, s, 0, 0, 0);
        float pv[16];
#pragma unroll
        for (int g = 0; g < 4; ++g) {
            f32x4 mv = *(const f32x4*)(tailadd + kt + 8 * g + 4 * kh);
#pragma unroll
            for (int r = 0; r < 4; ++r) {
                float e = __expf(s[g * 4 + r] + mv[r]);
                pv[g * 4 + r] = e;
                lsum += e;
            }
        }
#pragma unroll
        for (int g = 0; g < 4; ++g) {
            bf16x4 pb;
#pragma unroll
            for (int r = 0; r < 4; ++r) pb[r] = (__bf16)pv[g * 4 + r];
            *(bf16x4*)(Pw + cl * 32 + 8 * g + 4 * kh) = pb;
        }
        bf16x8 pf0 = *(const bf16x8*)(Pw + cl * 32 + kh * 8);
        bf16x8 pf1 = *(const bf16x8*)(Pw + cl * 32 + 16 + kh * 8);
        bf16x8 vf0 = *(const bf16x8*)(Vt + cl * 520 + kt + kh * 8);
        bf16x8 vf1 = *(const bf16x8*)(Vt + cl * 520 + kt + 16 + kh * 8);
        oacc = __builtin_amdgcn_mfma_f32_32x32x16_bf16(vf0, pf0, oacc, 0, 0, 0);
        oacc = __builtin_amdgcn_mfma_f32_32x32x16_bf16(vf1, pf1, oacc, 0, 0, 0);
    }

    lsum += __shfl_xor(lsum, 32);
    const float inv = (lsum > 0.f) ? 1.f / lsum : 0.f;
    __bf16* orow = ao + (size_t)(b * SEQ + tok0 + cl) * DMODEL + h * 32;
#pragma unroll
    for (int g = 0; g < 4; ++g) {
        bf16x4 w;
#pragma unroll
        for (int r = 0; r < 4; ++r) w[r] = (__bf16)(oacc[g * 4 + r] * inv);
        *(bf16x4*)(orow + 8 * g + 4 * kh) = w;
    }
}

// ---------------------------------------------------------------------------
// Fused GEMM + residual + LayerNorm, N=256 (Wo path). Unchanged.
// ---------------------------------------------------------------------------
template<int LAST>
__global__ __launch_bounds__(256, 4)
void gemm_ln_kernel(const __bf16* __restrict__ A, const __bf16* __restrict__ Bt,
                    const float* __restrict__ bias, const __bf16* __restrict__ res,
                    const float* __restrict__ g, const float* __restrict__ be,
                    __bf16* __restrict__ out16, float* __restrict__ out32, int K)
{
    __shared__ __bf16 As[32 * 64];
    __shared__ __bf16 Bs[256 * 64];
    __shared__ float red[32 * 8];
    const int tid = threadIdx.x;
    const int m0 = blockIdx.x * 32;
    const int lane = tid & 63;
    const int wave = tid >> 6;
    const int wn = wave * 64;
    const int fr = lane & 15;
    const int quad = lane >> 4;
    const int lr = lane >> 3;
    const int qg = (lane & 7) ^ lr;
    const int frs = fr & 7;

    const __bf16* Ab = A  + (size_t)(m0 + wave * 8 + lr) * K + qg * 8;
    const __bf16* Bb = Bt + (size_t)(wave * 64 + lr) * K + qg * 8;

    f32x4 acc[2][4];
#pragma unroll
    for (int i = 0; i < 2; ++i)
#pragma unroll
        for (int j = 0; j < 4; ++j)
#pragma unroll
            for (int r = 0; r < 4; ++r) acc[i][j][r] = 0.f;

    for (int k0 = 0; k0 < K; k0 += 64) {
        gll16(Ab + k0, As + wave * 512);
#pragma unroll
        for (int p = 0; p < 8; ++p)
            gll16(Bb + (size_t)p * 8 * K + k0, Bs + (wave * 8 + p) * 512);
        __syncthreads();
#pragma unroll
        for (int kk = 0; kk < 2; ++kk) {
            bf16x8 af[2], bfr[4];
#pragma unroll
            for (int i = 0; i < 2; ++i) {
                int row = i * 16 + fr;
                af[i] = *(const bf16x8*)(As + row * 64 + (((kk * 4 + quad) ^ frs) * 8));
            }
#pragma unroll
            for (int j = 0; j < 4; ++j) {
                int row = wn + j * 16 + fr;
                bfr[j] = *(const bf16x8*)(Bs + row * 64 + (((kk * 4 + quad) ^ frs) * 8));
            }
#pragma unroll
            for (int i = 0; i < 2; ++i)
#pragma unroll
                for (int j = 0; j < 4; ++j)
                    acc[i][j] = __builtin_amdgcn_mfma_f32_16x16x32_bf16(
                        af[i], bfr[j], acc[i][j], 0, 0, 0);
        }
        __syncthreads();
    }

    float bv[4];
#pragma unroll
    for (int j = 0; j < 4; ++j) bv[j] = bias[wn + j * 16 + fr];

#pragma unroll
    for (int i = 0; i < 2; ++i) {
#pragma unroll
        for (int r = 0; r < 4; ++r) {
            const int row = i * 16 + quad * 4 + r;
            float ps = 0.f, pq = 0.f;
#pragma unroll
            for (int j = 0; j < 4; ++j) {
                const int gc = wn + j * 16 + fr;
                float v = acc[i][j][r] + bv[j]
                        + (float)res[(size_t)(m0 + row) * DMODEL + gc];
                acc[i][j][r] = v;
                ps += v;
                pq += v * v;
            }
#pragma unroll
            for (int off = 1; off < 16; off <<= 1) {
                ps += __shfl_xor(ps, off, 64);
                pq += __shfl_xor(pq, off, 64);
            }
            if (fr == 0) {
                red[row * 8 + wave * 2]     = ps;
                red[row * 8 + wave * 2 + 1] = pq;
            }
        }
    }
    __syncthreads();

#pragma unroll
    for (int i = 0; i < 2; ++i) {
#pragma unroll
        for (int r = 0; r < 4; ++r) {
            const int row = i * 16 + quad * 4 + r;
            f32x4 a = *(const f32x4*)(red + row * 8);
            f32x4 b2 = *(const f32x4*)(red + row * 8 + 4);
            const float s  = a[0] + a[2] + b2[0] + b2[2];
            const float sq = a[1] + a[3] + b2[1] + b2[3];
            const float mu = s * (1.f / DMODEL);
            const float var = sq * (1.f / DMODEL) - mu * mu;
            const float rs = rsqrtf(var + 1e-5f);
#pragma unroll
            for (int j = 0; j < 4; ++j) {
                const int gc = wn + j * 16 + fr;
                float y = (acc[i][j][r] - mu) * rs * g[gc] + be[gc];
                if (LAST) out32[(size_t)(m0 + row) * DMODEL + gc] = y;
                else      out16[(size_t)(m0 + row) * DMODEL + gc] = (__bf16)y;
            }
        }
    }
}

// ---------------------------------------------------------------------------
// Fused FF block, transposed formulation (round 10, unchanged).
// ---------------------------------------------------------------------------
template<int LAST>
__global__ __launch_bounds__(256, 2)
void ff_kernel(const __bf16* __restrict__ A, const __bf16* __restrict__ w1A,
               const float* __restrict__ c1, const __bf16* __restrict__ w2A,
               const float* __restrict__ c2, const __bf16* __restrict__ res,
               const float* __restrict__ g, const float* __restrict__ be,
               __bf16* __restrict__ out16, float* __restrict__ out32)
{
    __shared__ __attribute__((aligned(16))) __bf16 As[4][32 * 64];
    __shared__ __attribute__((aligned(16))) __bf16 P[2][32 * 136];
    __shared__ float c1s[1024];
    __shared__ float red[32 * 8];
    const int tid = threadIdx.x;
    const int lane = tid & 63;
    const int wave = tid >> 6;
    const int fr = lane & 15;
    const int quad = lane >> 4;
    const int m0 = blockIdx.x * 32;

    {
        const int lr = lane >> 3, pos = lane & 7;
#pragma unroll
        for (int c4 = 0; c4 < 4; ++c4) {
            const int row = c4 * 8 + lr;
            const int gsw = pos ^ (row & 7);
            gll16(A + (size_t)(m0 + row) * 256 + wave * 64 + gsw * 8,
                  &As[wave][c4 * 8 * 64]);
        }
    }
    *(f32x4*)(c1s + tid * 4) = *(const f32x4*)(c1 + tid * 4);

    f32x4 acc2[4][2];
#pragma unroll
    for (int jj = 0; jj < 4; ++jj)
#pragma unroll
        for (int tt = 0; tt < 2; ++tt)
#pragma unroll
            for (int r = 0; r < 4; ++r) acc2[jj][tt][r] = 0.f;
    __syncthreads();

#pragma unroll 2
    for (int ch = 0; ch < 8; ++ch) {
        bf16x8 w2r[4][4];
#pragma unroll
        for (int jj = 0; jj < 4; ++jj)
#pragma unroll
            for (int ks = 0; ks < 4; ++ks) {
                const int dt = wave * 4 + jj, kt = ch * 4 + ks;
                w2r[jj][ks] = *(const bf16x8*)(w2A + ((size_t)(dt * 32 + kt) * 64 + lane) * 8);
            }
        f32x4 acc1[2][2];
#pragma unroll
        for (int i = 0; i < 2; ++i)
#pragma unroll
            for (int j = 0; j < 2; ++j)
#pragma unroll
                for (int r = 0; r < 4; ++r) acc1[i][j][r] = 0.f;
#pragma unroll
        for (int ks = 0; ks < 8; ++ks) {
            bf16x8 w1r[2], tf[2];
#pragma unroll
            for (int i = 0; i < 2; ++i) {
                const int ft = ch * 8 + wave * 2 + i;
                w1r[i] = *(const bf16x8*)(w1A + ((size_t)(ft * 8 + ks) * 64 + lane) * 8);
            }
#pragma unroll
            for (int j = 0; j < 2; ++j)
                tf[j] = *(const bf16x8*)(&As[ks >> 1][(j * 16 + fr) * 64
                          + ((((ks & 1) * 4 + quad) ^ (fr & 7)) * 8)]);
#pragma unroll
            for (int i = 0; i < 2; ++i)
#pragma unroll
                for (int j = 0; j < 2; ++j)
                    acc1[i][j] = __builtin_amdgcn_mfma_f32_16x16x32_bf16(
                        w1r[i], tf[j], acc1[i][j], 0, 0, 0);
        }
#pragma unroll
        for (int i = 0; i < 2; ++i) {
            f32x4 cb = *(const f32x4*)(c1s + ch * 128 + wave * 32 + i * 16 + quad * 4);
#pragma unroll
            for (int j = 0; j < 2; ++j) {
                bf16x4 pb;
#pragma unroll
                for (int r = 0; r < 4; ++r)
                    pb[r] = (__bf16)fmaxf(acc1[i][j][r] + cb[r], 0.f);
                *(bf16x4*)(&P[ch & 1][(j * 16 + fr) * 136 + wave * 32 + i * 16 + quad * 4]) = pb;
            }
        }
        __syncthreads();
#pragma unroll
        for (int ks = 0; ks < 4; ++ks) {
            bf16x8 pf[2];
#pragma unroll
            for (int tt = 0; tt < 2; ++tt)
                pf[tt] = *(const bf16x8*)(&P[ch & 1][(tt * 16 + fr) * 136 + ks * 32 + quad * 8]);
#pragma unroll
            for (int jj = 0; jj < 4; ++jj)
#pragma unroll
                for (int tt = 0; tt < 2; ++tt)
                    acc2[jj][tt] = __builtin_amdgcn_mfma_f32_16x16x32_bf16(
                        w2r[jj][ks], pf[tt], acc2[jj][tt], 0, 0, 0);
        }
    }

    float ps0 = 0.f, pq0 = 0.f, ps1 = 0.f, pq1 = 0.f;
#pragma unroll
    for (int jj = 0; jj < 4; ++jj) {
        f32x4 cb = *(const f32x4*)(c2 + wave * 64 + jj * 16 + quad * 4);
#pragma unroll
        for (int tt = 0; tt < 2; ++tt) {
            bf16x4 rv = *(const bf16x4*)(res + (size_t)(m0 + tt * 16 + fr) * DMODEL
                                         + wave * 64 + jj * 16 + quad * 4);
#pragma unroll
            for (int r = 0; r < 4; ++r) {
                float v = acc2[jj][tt][r] + cb[r] + (float)rv[r];
                acc2[jj][tt][r] = v;
                if (tt == 0) { ps0 += v; pq0 += v * v; }
                else         { ps1 += v; pq1 += v * v; }
            }
        }
    }
    ps0 += __shfl_xor(ps0, 16); ps0 += __shfl_xor(ps0, 32);
    pq0 += __shfl_xor(pq0, 16); pq0 += __shfl_xor(pq0, 32);
    ps1 += __shfl_xor(ps1, 16); ps1 += __shfl_xor(ps1, 32);
    pq1 += __shfl_xor(pq1, 16); pq1 += __shfl_xor(pq1, 32);
    if (quad == 0) {
        red[fr * 8 + wave * 2]            = ps0;
        red[fr * 8 + wave * 2 + 1]        = pq0;
        red[(16 + fr) * 8 + wave * 2]     = ps1;
        red[(16 + fr) * 8 + wave * 2 + 1] = pq1;
    }
    __syncthreads();
    float mu[2], rs_[2];
#pragma unroll
    for (int tt = 0; tt < 2; ++tt) {
        const int tok = tt * 16 + fr;
        f32x4 a = *(const f32x4*)(red + tok * 8);
        f32x4 b2 = *(const f32x4*)(red + tok * 8 + 4);
        const float s  = a[0] + a[2] + b2[0] + b2[2];
        const float sq = a[1] + a[3] + b2[1] + b2[3];
        mu[tt] = s * (1.f / DMODEL);
        const float var = sq * (1.f / DMODEL) - mu[tt] * mu[tt];
        rs_[tt] = rsqrtf(var + 1e-5f);
    }
#pragma unroll
    for (int jj = 0; jj < 4; ++jj) {
        f32x4 gv = *(const f32x4*)(g  + wave * 64 + jj * 16 + quad * 4);
        f32x4 bv = *(const f32x4*)(be + wave * 64 + jj * 16 + quad * 4);
#pragma unroll
        for (int tt = 0; tt < 2; ++tt) {
            const size_t base = (size_t)(m0 + tt * 16 + fr) * DMODEL
                              + wave * 64 + jj * 16 + quad * 4;
            if (LAST) {
                f32x4 y;
#pragma unroll
                for (int r = 0; r < 4; ++r)
                    y[r] = (acc2[jj][tt][r] - mu[tt]) * rs_[tt] * gv[r] + bv[r];
                *(f32x4*)(out32 + base) = y;
            } else {
                bf16x4 y;
#pragma unroll
                for (int r = 0; r < 4; ++r)
                    y[r] = (__bf16)((acc2[jj][tt][r] - mu[tt]) * rs_[tt] * gv[r] + bv[r]);
                *(bf16x4*)(out16 + base) = y;
            }
        }
    }
}

// ---------------------------------------------------------------------------
extern "C" void kernel_launch(void* const* d_in, const int* in_sizes, int n_in,
                              void* d_out, int out_size, void* d_ws, size_t ws_size,
                              hipStream_t stream)
{
    const float* x   = (const float*)d_in[0];
    const int*   mask= (const int*)d_in[1];
    const float* Win = (const float*)d_in[2];
    const float* bin = (const float*)d_in[3];
    const float* Wq  = (const float*)d_in[4];
    const float* bq  = (const float*)d_in[5];
    const float* Wk  = (const float*)d_in[6];
    const float* bk  = (const float*)d_in[7];
    const float* Wv  = (const float*)d_in[8];
    const float* bv  = (const float*)d_in[9];
    const float* Wo  = (const float*)d_in[10];
    const float* bo  = (const float*)d_in[11];
    const float* g1  = (const float*)d_in[12];
    const float* b1  = (const float*)d_in[13];
    const float* W1  = (const float*)d_in[14];
    const float* c1  = (const float*)d_in[15];
    const float* W2  = (const float*)d_in[16];
    const float* c2  = (const float*)d_in[17];
    const float* g2  = (const float*)d_in[18];
    const float* b2  = (const float*)d_in[19];

    char* ws = (char*)d_ws;
    size_t off = 0;
    auto alloc = [&](size_t bytes) -> void* {
        void* p = ws + off;
        off += (bytes + 255) & ~(size_t)255;
        return p;
    };
    __bf16* hA   = (__bf16*)alloc((size_t)MTOK * 256 * 2);
    __bf16* hB   = (__bf16*)alloc((size_t)MTOK * 256 * 2);
    __bf16* ao   = (__bf16*)alloc((size_t)MTOK * 256 * 2);
    __bf16* wqf  = (__bf16*)alloc((size_t)3 * 8 * 3 * 16 * 512 * 2);
    __bf16* wot  = (__bf16*)alloc((size_t)3 * 256 * 256 * 2);
    __bf16* w1f  = (__bf16*)alloc((size_t)3 * 1024 * 256 * 2);
    __bf16* w2f  = (__bf16*)alloc((size_t)3 * 256 * 1024 * 2);
    float*  bqkv = (float*)alloc((size_t)3 * 768 * 4);
    int*    pos  = (int*)alloc((size_t)BATCH * SEQ * 4);
    int*    nbp  = (int*)alloc((size_t)BATCH * 4);

    // prep: 2313 weight blocks + 2048 inproj + 32 mask-scan
    prep_kernel<<<dim3(4393), dim3(256), 0, stream>>>(
        Wq, Wk, Wv, Wo, W1, W2, bq, bk, bv, wqf, wot, w1f, w2f, bqkv,
        x, Win, bin, hA, mask, pos, nbp);

    for (int l = 0; l < NLAYER; ++l) {
        // fused QKV + attention (one block per (b,h)), compacted KV
        attn_kernel<<<dim3(256), dim3(1024), 0, stream>>>(
            hA, wqf + (size_t)l * 8 * 3 * 16 * 512, bqkv + l * 768, pos, nbp, ao);
        // Wo + residual + LN1 fused: hB = LN(hA + ao@Wo + bo)
        gemm_ln_kernel<0><<<dim3(MTOK / 32), dim3(256), 0, stream>>>(
            ao, wot + (size_t)l * 65536, bo + l * 256, hA,
            g1 + l * 256, b1 + l * 256, hB, nullptr, 256);
        // Fused FF block: hA = LN(hB + relu(hB@W1+c1)@W2 + c2)  (last -> d_out)
        if (l == 2) {
            ff_kernel<1><<<dim3(MTOK / 32), dim3(256), 0, stream>>>(
                hB, w1f + (size_t)l * 262144, c1 + l * 1024,
                w2f + (size_t)l * 262144, c2 + l * 256, hB,
                g2 + l * 256, b2 + l * 256, nullptr, (float*)d_out);
        } else {
            ff_kernel<0><<<dim3(MTOK / 32), dim3(256), 0, stream>>>(
                hB, w1f + (size_t)l * 262144, c1 + l * 1024,
                w2f + (size_t)l * 262144, c2 + l * 256, hB,
                g2 + l * 256, b2 + l * 256, hA, nullptr);
        }
    }
}